// Round 3
// baseline (741.878 us; speedup 1.0000x reference)
//
#include <hip/hip_runtime.h>
#include <hip/hip_bf16.h>
#include <stdint.h>

// Problem constants (from reference): B=4, N=65536, K=16, D=16
// Dtypes (established R0-R2): inputs fp32, indices int32 (int64 auto-detected),
// OUTPUT fp32 (reference returns float32; R2's bf16-out gave absmax ~ max|ref|).
#define NB    4
#define NN    65536
#define KK    16
#define DD    16
#define EPSB  1e-6f
#define MTOT  (NB*NN*KK)      // 4194304 samples for BN stats
#define NPTS  (NB*NN)         // 262144 points

// ws layout (float indices unless noted):
//   ws[0..31]    : stats  (sum_x[16], sum_x2[16])
//   ws[32..159]  : raw params   w0r[16], ur[48], werr[48], br[16]
//   int ws[160]  : index-width flag (1 = int64 indices, 0 = int32)
//   ws[192..319] : scaled params w0s[16], us[48], wers[48], bs[16]
//   byte 4096    : coords4  float4[NPTS]           (4 MB)
//   byte 4198400 : featT    bf16[NPTS*16]          (8 MB)
#define WSF_RAW    32
#define WSF_SCALED 192
#define WSI_FLAG   160
#define WSB_COORDS4 4096
#define WSB_FEATT   4198400

__device__ __forceinline__ ushort f2bf(float f) {
    uint u = __float_as_uint(f);
    u += 0x7fffu + ((u >> 16) & 1u);   // RNE
    return (ushort)(u >> 16);
}
__device__ __forceinline__ float bf2f(ushort u) {
    return __uint_as_float(((uint)u) << 16);
}

// Load indices for samples s0, s0+1 (s0 even), handling int32 or int64 storage.
__device__ __forceinline__ int2 load_idx_pair(const int* nidx, int s0, int is64) {
    if (is64) {
        int4 v = ((const int4*)nidx)[s0 >> 1];   // two little-endian int64s
        return make_int2(v.x, v.z);
    }
    return *(const int2*)(nidx + s0);
}

// ---------------------------------------------------------------------------
// K0: decompose conv weights, zero stats, detect index width.
//     f = [dist, rel3, ext3, nbr3];  x_o = w0*d + (w1+w4)·ext + (w7-w1)·nbr + b
__global__ void k_prep(const float* cw, const float* cb, const int* nidx, float* ws) {
    int t = threadIdx.x;
    if (t < 32) ws[t] = 0.0f;  // stats
    if (t == 0) {
        // int64 indices < 2^16 have zero high words at odd int32 positions.
        int hi = nidx[1] | nidx[3] | nidx[5] | nidx[7]
               | nidx[9] | nidx[11] | nidx[13] | nidx[15];
        ((int*)ws)[WSI_FLAG] = (hi == 0) ? 1 : 0;
    }
    if (t < 16) {
        float w[10];
        #pragma unroll
        for (int c = 0; c < 10; c++) w[c] = cw[t * 10 + c];
        float* raw = ws + WSF_RAW;
        raw[t] = w[0];                                  // w0r
        #pragma unroll
        for (int j = 0; j < 3; j++) {
            raw[16 + t * 3 + j] = w[7 + j] - w[1 + j];  // ur   (nbr coeff)
            raw[64 + t * 3 + j] = w[1 + j] + w[4 + j];  // werr (ext coeff)
        }
        raw[112 + t] = cb[t];                           // br
    }
}

// ---------------------------------------------------------------------------
// K1: gather-friendly tables: coords -> float4 (16B), features -> bf16 (b,n,16)
__global__ __launch_bounds__(256) void k_tables(const float* coords,
                                                const float* features,
                                                float4* coords4, ushort* featT) {
    int gid = blockIdx.x * 256 + threadIdx.x;       // point id in [0, NPTS)
    int b = gid >> 16, n = gid & 65535;
    const float* c = coords + (size_t)gid * 3;
    coords4[gid] = make_float4(c[0], c[1], c[2], 0.0f);
    uint pack[8];
    #pragma unroll
    for (int o = 0; o < 16; o++) {
        uint f = (uint)f2bf(features[(size_t)(b * 16 + o) * NN + n]); // coalesced
        if (o & 1) pack[o >> 1] |= f << 16;
        else       pack[o >> 1]  = f;
    }
    uint4* dst = (uint4*)(featT + (size_t)gid * 16);
    dst[0] = make_uint4(pack[0], pack[1], pack[2], pack[3]);
    dst[1] = make_uint4(pack[4], pack[5], pack[6], pack[7]);
}

// ---------------------------------------------------------------------------
// K2: BN statistics: per-channel sum and sum-of-squares over all samples.
__global__ __launch_bounds__(256) void k_stats(const int* nidx,
                                               const float4* coords4, float* ws) {
    const float* raw = ws + WSF_RAW;
    const int is64 = ((const int*)ws)[WSI_FLAG];
    float sx[16], sx2[16];
    #pragma unroll
    for (int o = 0; o < 16; o++) { sx[o] = 0.0f; sx2[o] = 0.0f; }

    int tid0 = blockIdx.x * 256 + threadIdx.x;      // 1024 blocks -> 262144 threads
    for (int p = tid0; p < MTOT / 2; p += 262144) { // 8 sample-pairs per thread
        int s0 = 2 * p;
        int pt = s0 >> 4;                           // global point
        int b  = pt >> 16;
        int2 ii = load_idx_pair(nidx, s0, is64);
        float4 ec = coords4[pt];
        float4 a0 = coords4[(b << 16) + ii.x];
        float4 a1 = coords4[(b << 16) + ii.y];
        float r0x = ec.x - a0.x, r0y = ec.y - a0.y, r0z = ec.z - a0.z;
        float r1x = ec.x - a1.x, r1y = ec.y - a1.y, r1z = ec.z - a1.z;
        float d0 = sqrtf(r0x * r0x + r0y * r0y + r0z * r0z);
        float d1 = sqrtf(r1x * r1x + r1y * r1y + r1z * r1z);
        #pragma unroll
        for (int o = 0; o < 16; o++) {
            float base = raw[112 + o] + raw[64 + o * 3] * ec.x
                       + raw[64 + o * 3 + 1] * ec.y + raw[64 + o * 3 + 2] * ec.z;
            float x0 = base + raw[o] * d0 + raw[16 + o * 3] * a0.x
                     + raw[16 + o * 3 + 1] * a0.y + raw[16 + o * 3 + 2] * a0.z;
            float x1 = base + raw[o] * d1 + raw[16 + o * 3] * a1.x
                     + raw[16 + o * 3 + 1] * a1.y + raw[16 + o * 3 + 2] * a1.z;
            sx[o]  += x0 + x1;
            sx2[o] += x0 * x0 + x1 * x1;
        }
    }
    __shared__ float ssum[32];
    if (threadIdx.x < 32) ssum[threadIdx.x] = 0.0f;
    __syncthreads();
    #pragma unroll
    for (int o = 0; o < 16; o++) {
        atomicAdd(&ssum[o], sx[o]);
        atomicAdd(&ssum[16 + o], sx2[o]);
    }
    __syncthreads();
    if (threadIdx.x < 32) atomicAdd(&ws[threadIdx.x], ssum[threadIdx.x]);
}

// ---------------------------------------------------------------------------
// K3: finalize: fold BN (mean/var/gamma/beta) into scaled conv params.
__global__ void k_final(const float* gamma, const float* beta, float* ws) {
    int o = threadIdx.x;
    if (o >= 16) return;
    const float inv_m = 1.0f / (float)MTOT;
    float mean = ws[o] * inv_m;
    float var  = ws[16 + o] * inv_m - mean * mean;
    float a = gamma[o] * rsqrtf(var + EPSB);
    float c = beta[o] - mean * a;
    const float* raw = ws + WSF_RAW;
    float* sc = ws + WSF_SCALED;
    sc[o] = a * raw[o];
    #pragma unroll
    for (int j = 0; j < 3; j++) {
        sc[16 + o * 3 + j] = a * raw[16 + o * 3 + j];
        sc[64 + o * 3 + j] = a * raw[64 + o * 3 + j];
    }
    sc[112 + o] = a * raw[112 + o] + c;
}

// ---------------------------------------------------------------------------
// K4: main fused kernel, fp32 output. Block = 32 points x 16 neighbors = 512
//     samples. Two passes through one 16ch x 512 fp32 LDS tile (32 KB):
//     pass 1 = gathered features (ch 0..15), pass 2 = spatial encoding (16..31).
__global__ __launch_bounds__(256, 4) void k_main(const int* nidx,
                                                 const float4* coords4,
                                                 const ushort* featT,
                                                 const float* ws, float* out) {
    __shared__ float lout[16 * 512];    // 32 KB, reused across both passes
    const float* sc = ws + WSF_SCALED;  // uniform -> scalar loads
    const int is64 = ((const int*)ws)[WSI_FLAG];
    int t = threadIdx.x;
    int point0 = blockIdx.x * 32;       // 8192 blocks; b uniform within block
    int b = point0 >> 16;
    int n0k = (point0 & 65535) * 16;    // n0 * K

    // Thread t handles samples 2t, 2t+1 (same point pt, adjacent k)
    int pt = t >> 3;
    int k0 = (t & 7) * 2;
    int pg = point0 + pt;
    int2 ii = load_idx_pair(nidx, pg * 16 + k0, is64);
    float4 ec = coords4[pg];
    float4 a0 = coords4[(b << 16) + ii.x];
    float4 a1 = coords4[(b << 16) + ii.y];
    const uint4* f0p = (const uint4*)(featT + (size_t)((b << 16) + ii.x) * 16);
    const uint4* f1p = (const uint4*)(featT + (size_t)((b << 16) + ii.y) * 16);
    uint4 fa0 = f0p[0], fa1 = f0p[1];
    uint4 fb0 = f1p[0], fb1 = f1p[1];

    int spos = t * 2;

    // ---- Pass 1: gathered neighbor features -> channels 0..15 ----
    uint fw0[8] = {fa0.x, fa0.y, fa0.z, fa0.w, fa1.x, fa1.y, fa1.z, fa1.w};
    uint fw1[8] = {fb0.x, fb0.y, fb0.z, fb0.w, fb1.x, fb1.y, fb1.z, fb1.w};
    #pragma unroll
    for (int o = 0; o < 16; o++) {
        float va = bf2f((ushort)((fw0[o >> 1] >> ((o & 1) * 16)) & 0xffffu));
        float vb = bf2f((ushort)((fw1[o >> 1] >> ((o & 1) * 16)) & 0xffffu));
        *(float2*)&lout[o * 512 + spos] = make_float2(va, vb);
    }
    __syncthreads();
    #pragma unroll
    for (int j = 0; j < 8; j++) {
        int L = j * 256 + t;
        int ch = L >> 7;                 // 128 threads per 512-float row
        int off = (L & 127) * 4;
        float4 v = *(const float4*)&lout[ch * 512 + off];
        size_t eidx = ((size_t)(b * 32 + ch) << 20) + (size_t)(n0k + off);
        *(float4*)(out + eidx) = v;
    }
    __syncthreads();

    // ---- Pass 2: spatial encoding y = relu(w'·f + b') -> channels 16..31 ----
    float r0x = ec.x - a0.x, r0y = ec.y - a0.y, r0z = ec.z - a0.z;
    float r1x = ec.x - a1.x, r1y = ec.y - a1.y, r1z = ec.z - a1.z;
    float d0 = sqrtf(r0x * r0x + r0y * r0y + r0z * r0z);
    float d1 = sqrtf(r1x * r1x + r1y * r1y + r1z * r1z);
    #pragma unroll
    for (int o = 0; o < 16; o++) {
        float base = sc[112 + o] + sc[64 + o * 3] * ec.x
                   + sc[64 + o * 3 + 1] * ec.y + sc[64 + o * 3 + 2] * ec.z;
        float x0 = base + sc[o] * d0 + sc[16 + o * 3] * a0.x
                 + sc[16 + o * 3 + 1] * a0.y + sc[16 + o * 3 + 2] * a0.z;
        float x1 = base + sc[o] * d1 + sc[16 + o * 3] * a1.x
                 + sc[16 + o * 3 + 1] * a1.y + sc[16 + o * 3 + 2] * a1.z;
        *(float2*)&lout[o * 512 + spos] =
            make_float2(fmaxf(x0, 0.0f), fmaxf(x1, 0.0f));
    }
    __syncthreads();
    #pragma unroll
    for (int j = 0; j < 8; j++) {
        int L = j * 256 + t;
        int ch = L >> 7;
        int off = (L & 127) * 4;
        float4 v = *(const float4*)&lout[ch * 512 + off];
        size_t eidx = ((size_t)(b * 32 + 16 + ch) << 20) + (size_t)(n0k + off);
        *(float4*)(out + eidx) = v;
    }
}

// ---------------------------------------------------------------------------
extern "C" void kernel_launch(void* const* d_in, const int* in_sizes, int n_in,
                              void* d_out, int out_size, void* d_ws, size_t ws_size,
                              hipStream_t stream) {
    const float* coords   = (const float*)d_in[0];   // fp32 (B,N,3)
    const float* features = (const float*)d_in[1];   // fp32 (B,D,N,1)
    const int*   nidx     = (const int*)d_in[2];     // int32 (or int64) (B,N,K)
    const float* conv_w   = (const float*)d_in[3];   // fp32 (D,10)
    const float* conv_b   = (const float*)d_in[4];   // fp32 (D,)
    const float* gamma    = (const float*)d_in[5];   // fp32 (D,)
    const float* beta     = (const float*)d_in[6];   // fp32 (D,)
    float*   ws      = (float*)d_ws;
    float4*  coords4 = (float4*)((char*)d_ws + WSB_COORDS4);
    ushort*  featT   = (ushort*)((char*)d_ws + WSB_FEATT);
    float*   out     = (float*)d_out;

    hipLaunchKernelGGL(k_prep,   dim3(1),    dim3(64),  0, stream, conv_w, conv_b, nidx, ws);
    hipLaunchKernelGGL(k_tables, dim3(NPTS / 256), dim3(256), 0, stream,
                       coords, features, coords4, featT);
    hipLaunchKernelGGL(k_stats,  dim3(1024), dim3(256), 0, stream, nidx, coords4, ws);
    hipLaunchKernelGGL(k_final,  dim3(1),    dim3(16),  0, stream, gamma, beta, ws);
    hipLaunchKernelGGL(k_main,   dim3(NPTS / 32), dim3(256), 0, stream,
                       nidx, coords4, featT, ws, out);
}